// Round 1
// 916.250 us; speedup vs baseline: 1.0115x; 1.0115x over previous
//
#include <hip/hip_runtime.h>
#include <stdint.h>

// Problem constants
#define B_   2
#define S_   2048
#define D_   1024
#define H_   16
#define DK_  64
#define DFF_ 4096
#define M_   (B_ * S_)   // 4096 rows total

typedef unsigned short u16;
typedef unsigned int   u32;
typedef __attribute__((ext_vector_type(8))) short short8;  // 8 bf16 (4 VGPRs)
typedef __attribute__((ext_vector_type(4))) float f32x4;   // MFMA C/D

// ---------- bf16 <-> f32 helpers ----------
__device__ __forceinline__ float b2f(u16 u) {
  union { u32 i; float f; } z; z.i = ((u32)u) << 16; return z.f;
}
__device__ __forceinline__ u16 f2b(float f) {
  union { float f; u32 i; } z; z.f = f;
  u32 x = z.i;
  u32 r = (x + 0x7fffu + ((x >> 16) & 1u)) >> 16;
  return (u16)r;
}

// load 4 consecutive elems as fp32 from fp32 or bf16 backing
__device__ __forceinline__ void load4(const float* p, float* f) {
  float4 v = *(const float4*)p;
  f[0] = v.x; f[1] = v.y; f[2] = v.z; f[3] = v.w;
}
__device__ __forceinline__ void load4(const u16* p, float* f) {
  uint2 v = *(const uint2*)p;
  f[0] = b2f(v.x & 0xffffu); f[1] = b2f(v.x >> 16);
  f[2] = b2f(v.y & 0xffffu); f[3] = b2f(v.y >> 16);
}
__device__ __forceinline__ void tstore(float* p, float v) { *p = v; }
__device__ __forceinline__ void tstore(u16* p, float v)   { *p = f2b(v); }
__device__ __forceinline__ float tload(const float* p) { return *p; }
__device__ __forceinline__ float tload(const u16* p)   { return b2f(*p); }

// ---------- MFMA GEMM: C[M,N] = (A@W + bias)*oscale (+ReLU) (+res) ----------
// A: fp32 or bf16 global. W/bias: fp32 global. C/res: fp32 or bf16.
// 128x128 tile, BK=32, 256 threads = 4 waves, each wave 64x64 (4x4 MFMA
// tiles of 16x16x32 bf16). fp32->bf16 conversion happens in staging.
// LDS rows are 40 u16 = 80 B (20 dwords, gcd(20,32)=4 -> rotating banks).
// MFMA layouts (verified round 7): A[m=lane&15][k=quad*8+j],
// B[n=lane&15][k=quad*8+j], D[row=quad*4+r][col=lane&15], row = A's m.
template<bool RELU, bool RES, typename TA, typename TO>
__global__ __launch_bounds__(256)
void gemm_mfma(const TA* __restrict__ A, const float* __restrict__ W,
               const float* __restrict__ bias, const TO* __restrict__ res,
               TO* __restrict__ C, int M, int N, int K, float oscale)
{
  __shared__ u16 As[128][40];   // [m][k] k-contiguous
  __shared__ u16 Bs[128][40];   // [n][k] k-contiguous (W transposed)

  const int tid  = threadIdx.x;
  const int wave = tid >> 6;
  const int lane = tid & 63;
  const int lo16 = lane & 15;
  const int quad = lane >> 4;
  const int row0 = blockIdx.y * 128;
  const int col0 = blockIdx.x * 128;
  const int mb   = (wave & 1) * 64;
  const int nb   = (wave >> 1) * 64;

  f32x4 acc[4][4];
#pragma unroll
  for (int i = 0; i < 4; ++i)
#pragma unroll
    for (int j = 0; j < 4; ++j) acc[i][j] = (f32x4){0.f, 0.f, 0.f, 0.f};

  // A staging: thread covers rows {rg, rg+32, rg+64, rg+96}, k-quarter kq*4
  const int a_kq = tid & 7;
  const int a_rg = tid >> 3;
  // W staging: thread covers col b_n, k-half b_h*16
  const int b_n = tid & 127;
  const int b_h = tid >> 7;

  for (int k0 = 0; k0 < K; k0 += 32) {
    // stage A (fp32/bf16 -> bf16)
#pragma unroll
    for (int rep = 0; rep < 4; ++rep) {
      const int r = a_rg + rep * 32;
      float f[4];
      load4(A + (size_t)(row0 + r) * K + k0 + a_kq * 4, f);
      uint2 pk;
      pk.x = (u32)f2b(f[0]) | ((u32)f2b(f[1]) << 16);
      pk.y = (u32)f2b(f[2]) | ((u32)f2b(f[3]) << 16);
      *(uint2*)&As[r][a_kq * 4] = pk;
    }
    // stage W transposed (fp32 -> bf16): 16 coalesced scalar loads
    {
      u16 wt[16];
#pragma unroll
      for (int i = 0; i < 16; ++i)
        wt[i] = f2b(W[(size_t)(k0 + b_h * 16 + i) * N + col0 + b_n]);
      uint4 p0, p1;
      p0.x = (u32)wt[0]  | ((u32)wt[1]  << 16);
      p0.y = (u32)wt[2]  | ((u32)wt[3]  << 16);
      p0.z = (u32)wt[4]  | ((u32)wt[5]  << 16);
      p0.w = (u32)wt[6]  | ((u32)wt[7]  << 16);
      p1.x = (u32)wt[8]  | ((u32)wt[9]  << 16);
      p1.y = (u32)wt[10] | ((u32)wt[11] << 16);
      p1.z = (u32)wt[12] | ((u32)wt[13] << 16);
      p1.w = (u32)wt[14] | ((u32)wt[15] << 16);
      *(uint4*)&Bs[b_n][b_h * 16] = p0;
      *(uint4*)&Bs[b_n][b_h * 16 + 8] = p1;
    }
    __syncthreads();

    short8 af[4], bf[4];
#pragma unroll
    for (int mi = 0; mi < 4; ++mi)
      af[mi] = *(const short8*)&As[mb + mi * 16 + lo16][quad * 8];
#pragma unroll
    for (int ni = 0; ni < 4; ++ni)
      bf[ni] = *(const short8*)&Bs[nb + ni * 16 + lo16][quad * 8];
#pragma unroll
    for (int mi = 0; mi < 4; ++mi)
#pragma unroll
      for (int ni = 0; ni < 4; ++ni)
        acc[mi][ni] = __builtin_amdgcn_mfma_f32_16x16x32_bf16(af[mi], bf[ni], acc[mi][ni], 0, 0, 0);
    __syncthreads();
  }

  // epilogue
  float bv[4];
#pragma unroll
  for (int ni = 0; ni < 4; ++ni) bv[ni] = bias[col0 + nb + ni * 16 + lo16];
#pragma unroll
  for (int mi = 0; mi < 4; ++mi) {
#pragma unroll
    for (int ni = 0; ni < 4; ++ni) {
      const int col = col0 + nb + ni * 16 + lo16;
#pragma unroll
      for (int r = 0; r < 4; ++r) {
        const int row = row0 + mb + mi * 16 + quad * 4 + r;
        float vv = (acc[mi][ni][r] + bv[ni]) * oscale;
        if (RELU) vv = fmaxf(vv, 0.f);
        if (RES)  vv += tload(res + (size_t)row * N + col);
        tstore(C + (size_t)row * N + col, vv);
      }
    }
  }
}

// ---------- bf16 transpose: out[D_][M_] = in[M_][D_]^T ----------
// 64x64 tiles, 256 threads, coalesced uint2 on both sides via LDS.
// V is dead after attention, so Vt enables 16B vector B-fragment loads in
// attention phase B (replaces 128 stride-2KB scalar gathers per wave-step).
__global__ __launch_bounds__(256)
void transpose_bf16(const u16* __restrict__ in, u16* __restrict__ out)
{
  __shared__ u16 tile[64][68];
  const int t  = threadIdx.x;
  const int r0 = blockIdx.x * 64;   // token dim (M_)
  const int c0 = blockIdx.y * 64;   // feature dim (D_)
  const int rr = t >> 4;            // 0..15
  const int cc = (t & 15) * 4;      // 0..60
#pragma unroll
  for (int rep = 0; rep < 4; ++rep) {
    uint2 vv = *(const uint2*)(in + (size_t)(r0 + rr + rep * 16) * D_ + c0 + cc);
    *(uint2*)&tile[rr + rep * 16][cc] = vv;
  }
  __syncthreads();
#pragma unroll
  for (int rep = 0; rep < 4; ++rep) {
    const int dr = rr + rep * 16;   // feature within tile
    uint2 o;
    o.x = (u32)tile[cc + 0][dr] | ((u32)tile[cc + 1][dr] << 16);
    o.y = (u32)tile[cc + 2][dr] | ((u32)tile[cc + 3][dr] << 16);
    *(uint2*)(out + (size_t)(c0 + dr) * M_ + r0 + cc) = o;
  }
}

// ---------- MFMA attention, head-axis softmax, producer/consumer ----------
// Block = 16 q-rows, 1024 threads (16 waves), grid 256 = 1 block/CU.
// Wave specialization with double-buffered weights (Ws[2], 128 KB LDS):
//   producers (waves 0..7): wave w owns t-chunk [t0+w*16,+16). Per 128-t
//     step: 16 heads x 2 MFMAs scores (Q,K frags from global, L1/L2-hot),
//     in-register softmax over the head axis (16 head values for a (q,t)
//     live in the same lane+reg across the 16 accumulators), bf16 weights
//     to Ws[buf] with XOR swizzle pos = t ^ ((q&7)<<3).
//   consumers (waves 8..15): wave owns 2 heads. A-frag = aligned
//     ds_read_b128 from Ws[buf^1], B-frag = 16B vector load from Vt
//     (pre-transposed V: 8 consecutive t per lane). 2h x 4kc x 4dt MFMAs.
// One barrier per step; every wave works every step (vs. old serial
// phase A with 8 idle waves + scalar V gather: MfmaUtil was 3.5%).
__global__ __launch_bounds__(1024)
void attention_mfma(const u16* __restrict__ q, const u16* __restrict__ k,
                    const u16* __restrict__ vt, u16* __restrict__ ctx)
{
  __shared__ __align__(16) u16 Ws[2][16][16][128];  // 131,072 B

  const int tid  = threadIdx.x;
  const int wave = tid >> 6;
  const int lane = tid & 63;
  const int lo16 = lane & 15;
  const int quad = lane >> 4;

  const int qrow0 = blockIdx.x * 16;
  const int batch = blockIdx.x >> 7;

  if (wave < 8) {
    // ================= producer =================
    const int tloc = wave * 16;
    const u16* qrow = q + (size_t)(qrow0 + lo16) * D_ + quad * 8;
    const u16* kbp  = k + (size_t)batch * S_ * D_;

    for (int s = 0; s < 16; ++s) {
      const int t0 = s * 128;
      u16 (*W)[16][128] = Ws[s & 1];
      const u16* krow = kbp + (size_t)(t0 + tloc + lo16) * D_ + quad * 8;

      f32x4 Sg[16];
#pragma unroll
      for (int h = 0; h < 16; ++h) {
        short8 a0 = *(const short8*)(qrow + h * 64);
        short8 b0 = *(const short8*)(krow + h * 64);
        short8 a1 = *(const short8*)(qrow + h * 64 + 32);
        short8 b1 = *(const short8*)(krow + h * 64 + 32);
        f32x4 sc = (f32x4){0.f, 0.f, 0.f, 0.f};
        sc = __builtin_amdgcn_mfma_f32_16x16x32_bf16(a0, b0, sc, 0, 0, 0);
        sc = __builtin_amdgcn_mfma_f32_16x16x32_bf16(a1, b1, sc, 0, 0, 0);
        Sg[h] = sc;
      }
      // in-register softmax over heads (1/sqrt(dk) pre-folded into q)
#pragma unroll
      for (int r = 0; r < 4; ++r) {
        float m = Sg[0][r];
#pragma unroll
        for (int h = 1; h < 16; ++h) m = fmaxf(m, Sg[h][r]);
        float sum = 0.f;
#pragma unroll
        for (int h = 0; h < 16; ++h) {
          float e = __expf(Sg[h][r] - m);
          Sg[h][r] = e;
          sum += e;
        }
        float rinv = 1.0f / sum;
        const int qq  = quad * 4 + r;                      // q-index (C/D row)
        const int pos = (tloc + lo16) ^ ((qq & 7) << 3);   // swizzled t slot
#pragma unroll
        for (int h = 0; h < 16; ++h) {
          union { float f; u32 u; } z; z.f = Sg[h][r] * rinv;
          W[h][qq][pos] = (u16)((z.u + 0x8000u) >> 16);
        }
      }
      __syncthreads();   // publish Ws[s&1]
    }
    __syncthreads();     // pair with consumer's final in-loop barrier
  } else {
    // ================= consumer =================
    const int h0 = (wave - 8) * 2;
    f32x4 acc[2][4];
#pragma unroll
    for (int i = 0; i < 2; ++i)
#pragma unroll
      for (int j = 0; j < 4; ++j) acc[i][j] = (f32x4){0.f, 0.f, 0.f, 0.f};

    // step-invariant Vt row bases: Vt[d][batch*S_+t], d = h*64+dt*16+lo16
    const u16* vbase[2][4];
#pragma unroll
    for (int hh = 0; hh < 2; ++hh)
#pragma unroll
      for (int dt = 0; dt < 4; ++dt)
        vbase[hh][dt] = vt + (size_t)((h0 + hh) * 64 + dt * 16 + lo16) * M_
                           + (size_t)batch * S_ + quad * 8;

    __syncthreads();     // wait for Ws[0]
    for (int s = 0; s < 16; ++s) {
      const int t0 = s * 128;
      const u16 (*W)[16][128] = Ws[s & 1];
#pragma unroll
      for (int kc = 0; kc < 4; ++kc) {
        const int kbase = kc * 32 + quad * 8;              // un-swizzled t-local
        const int ksw   = kbase ^ ((lo16 & 7) << 3);
#pragma unroll
        for (int hh = 0; hh < 2; ++hh) {
          short8 aw = *(const short8*)&W[h0 + hh][lo16][ksw];
#pragma unroll
          for (int dt = 0; dt < 4; ++dt) {
            short8 bv = *(const short8*)(vbase[hh][dt] + t0 + kc * 32);
            acc[hh][dt] = __builtin_amdgcn_mfma_f32_16x16x32_bf16(aw, bv, acc[hh][dt], 0, 0, 0);
          }
        }
      }
      __syncthreads();   // done with Ws[s&1]; producers may refill it
    }

    // write ctx (D row = q = quad*4+r, col = lo16)
    u16* crow = ctx + (size_t)(qrow0 + quad * 4) * D_ + lo16;
#pragma unroll
    for (int hh = 0; hh < 2; ++hh)
#pragma unroll
      for (int dt = 0; dt < 4; ++dt)
#pragma unroll
        for (int r = 0; r < 4; ++r)
          crow[(size_t)r * D_ + (h0 + hh) * 64 + dt * 16] = f2b(acc[hh][dt][r]);
  }
}

// ---------- (x [+ y]) -> LayerNorm (D=1024, one block per row) ----------
__device__ __forceinline__ float block_sum(float vv, float* sm) {
#pragma unroll
  for (int o = 32; o > 0; o >>= 1) vv += __shfl_down(vv, o);
  __syncthreads();
  if ((threadIdx.x & 63) == 0) sm[threadIdx.x >> 6] = vv;
  __syncthreads();
  return sm[0] + sm[1] + sm[2] + sm[3];
}

template<typename TX, bool HAS_Y, typename TO>
__global__ __launch_bounds__(256)
void add_ln(const TX* __restrict__ x, const u16* __restrict__ y,
            const float* __restrict__ g, const float* __restrict__ bta,
            TO* __restrict__ out)
{
  __shared__ float sm[4];
  const int row = blockIdx.x;
  const int t   = threadIdx.x;
  const size_t base = (size_t)row * D_ + t * 4;

  float s[4];
  load4(x + base, s);
  if (HAS_Y) {
    float yv[4];
    load4(y + base, yv);
    s[0] += yv[0]; s[1] += yv[1]; s[2] += yv[2]; s[3] += yv[3];
  }

  float loc = s[0] + s[1] + s[2] + s[3];
  float tot = block_sum(loc, sm);
  float mean = tot * (1.f / 1024.f);
  float d0 = s[0] - mean, d1 = s[1] - mean, d2 = s[2] - mean, d3 = s[3] - mean;
  float sq = d0 * d0 + d1 * d1 + d2 * d2 + d3 * d3;
  float tv = block_sum(sq, sm);
  float rstd = rsqrtf(tv * (1.f / 1024.f) + 1e-5f);

  float4 gv = *(const float4*)(g + t * 4);
  float4 bv = *(const float4*)(bta + t * 4);
  float o0 = d0 * rstd * gv.x + bv.x;
  float o1 = d1 * rstd * gv.y + bv.y;
  float o2 = d2 * rstd * gv.z + bv.z;
  float o3 = d3 * rstd * gv.w + bv.w;
  if (sizeof(TO) == 4) {
    *(float4*)((float*)out + base) = make_float4(o0, o1, o2, o3);
  } else {
    uint2 ov;
    ov.x = (u32)f2b(o0) | ((u32)f2b(o1) << 16);
    ov.y = (u32)f2b(o2) | ((u32)f2b(o3) << 16);
    *(uint2*)((u16*)out + base) = ov;
  }
}

// ---------- launch ----------
// Inputs fp32, output fp32. Intermediates bf16 in ws. Peak ws = 33.55 MB.
//   slot0: q -> ao -> h1[0] | slot1: k | slot2: v -> ctx -> h1[2]
//   slot3: vt (V transposed) | d_out(fp32): x1 -> z -> final LN in-place
extern "C" void kernel_launch(void* const* d_in, const int* in_sizes, int n_in,
                              void* d_out, int out_size, void* d_ws, size_t ws_size,
                              hipStream_t stream) {
  const float* x     = (const float*)d_in[0];
  const float* wq    = (const float*)d_in[1];
  const float* bq    = (const float*)d_in[2];
  const float* wk    = (const float*)d_in[3];
  const float* bk    = (const float*)d_in[4];
  const float* wv    = (const float*)d_in[5];
  const float* bv    = (const float*)d_in[6];
  const float* wo    = (const float*)d_in[7];
  const float* bo    = (const float*)d_in[8];
  const float* g1    = (const float*)d_in[9];
  const float* beta1 = (const float*)d_in[10];
  const float* w1    = (const float*)d_in[11];
  const float* b1    = (const float*)d_in[12];
  const float* w2    = (const float*)d_in[13];
  const float* b2    = (const float*)d_in[14];
  const float* g2    = (const float*)d_in[15];
  const float* beta2 = (const float*)d_in[16];
  float* outF = (float*)d_out;

  u16* ws = (u16*)d_ws;
  const size_t MD = (size_t)M_ * D_;
  u16* q   = ws + 0 * MD;
  u16* kb  = ws + 1 * MD;
  u16* vb  = ws + 2 * MD;
  u16* vt  = ws + 3 * MD;
  u16* ctx = ws + 2 * MD;   // overwrites vb (dead after transpose)
  u16* ao  = ws + 0 * MD;   // overwrites q (dead after attention)
  float* x1 = outF;
  u16* h1  = ws + 0 * MD;
  float* z  = outF;

  dim3 blk(256);
  // QKV projections; 1/sqrt(dk)=0.125 folded into q
  gemm_mfma<false, false><<<dim3(D_ / 128, M_ / 128), blk, 0, stream>>>(x, wq, bq, (const u16*)nullptr, q,  M_, D_, D_, 0.125f);
  gemm_mfma<false, false><<<dim3(D_ / 128, M_ / 128), blk, 0, stream>>>(x, wk, bk, (const u16*)nullptr, kb, M_, D_, D_, 1.0f);
  gemm_mfma<false, false><<<dim3(D_ / 128, M_ / 128), blk, 0, stream>>>(x, wv, bv, (const u16*)nullptr, vb, M_, D_, D_, 1.0f);
  // Vt = V^T (enables vectorized B-fragment loads in attention phase B)
  transpose_bf16<<<dim3(M_ / 64, D_ / 64), blk, 0, stream>>>(vb, vt);
  // fused MFMA attention (head-axis softmax), producer/consumer waves
  attention_mfma<<<dim3(M_ / 16), dim3(1024), 0, stream>>>(q, kb, vt, ctx);
  // output projection
  gemm_mfma<false, false><<<dim3(D_ / 128, M_ / 128), blk, 0, stream>>>(ctx, wo, bo, (const u16*)nullptr, ao, M_, D_, D_, 1.0f);
  // x1 = LN(x + attn_out)
  add_ln<float, true, float><<<dim3(M_), blk, 0, stream>>>(x, ao, g1, beta1, x1);
  // FFN1: h1 = relu(x1 @ w1 + b1)
  gemm_mfma<true, false><<<dim3(DFF_ / 128, M_ / 128), blk, 0, stream>>>(x1, w1, b1, (const u16*)nullptr, h1, M_, DFF_, D_, 1.0f);
  // FFN2 + residual x1, in-place over d_out
  gemm_mfma<false, true><<<dim3(D_ / 128, M_ / 128), blk, 0, stream>>>(h1, w2, b2, (const float*)x1, z, M_, D_, DFF_, 1.0f);
  // out = LN(z), in-place on d_out
  add_ln<float, false, float><<<dim3(M_), blk, 0, stream>>>(z, (const u16*)nullptr, g2, beta2, outF);
}

// Round 4
// 685.630 us; speedup vs baseline: 1.3518x; 1.3364x over previous
//
#include <hip/hip_runtime.h>
#include <stdint.h>

// Problem constants
#define B_   2
#define S_   2048
#define D_   1024
#define H_   16
#define DK_  64
#define DFF_ 4096
#define M_   (B_ * S_)   // 4096 rows total
#define QKV_LD 3072      // fused qkv row stride

typedef unsigned short u16;
typedef unsigned int   u32;
typedef __attribute__((ext_vector_type(8))) short short8;  // 8 bf16 (4 VGPRs)
typedef __attribute__((ext_vector_type(4))) float f32x4;   // MFMA C/D

// ---------- bf16 <-> f32 helpers ----------
__device__ __forceinline__ float b2f(u16 u) {
  union { u32 i; float f; } z; z.i = ((u32)u) << 16; return z.f;
}
__device__ __forceinline__ u16 f2b(float f) {
  union { float f; u32 i; } z; z.f = f;
  u32 x = z.i;
  u32 r = (x + 0x7fffu + ((x >> 16) & 1u)) >> 16;
  return (u16)r;
}
__device__ __forceinline__ void load4(const float* p, float* f) {
  float4 v = *(const float4*)p;
  f[0] = v.x; f[1] = v.y; f[2] = v.z; f[3] = v.w;
}
__device__ __forceinline__ void load4(const u16* p, float* f) {
  uint2 v = *(const uint2*)p;
  f[0] = b2f(v.x & 0xffffu); f[1] = b2f(v.x >> 16);
  f[2] = b2f(v.y & 0xffffu); f[3] = b2f(v.y >> 16);
}
__device__ __forceinline__ void tstore(float* p, float v) { *p = v; }
__device__ __forceinline__ void tstore(u16* p, float v)   { *p = f2b(v); }

// async global->LDS, 16 B per lane (dest = wave-uniform base + lane*16)
__device__ __forceinline__ void gld_lds16(const void* g, void* l) {
  __builtin_amdgcn_global_load_lds(
      (const __attribute__((address_space(1))) void*)g,
      (__attribute__((address_space(3))) void*)l, 16, 0, 0);
}

// ---------- m97-style MFMA GEMM: C = (A @ Wt^T + bias)*osc (+ReLU)(+res) ----
// A: bf16 [M][K] k-contig. Wt: bf16 [N][K] k-contig (pre-transposed weight).
// Tile BM x 128, BK=32, 256 threads = 4 waves (2x2), wave tile (BM/2) x 64.
// Staging via global_load_lds dwordx4 into linear [rows][32] bf16 LDS
// (64 B rows -> b128 frag reads alternate bank halves, BW-optimal, no
// swizzle needed; m201's 16-way conflict only appears at 128 B rows).
// MFMA layouts (carried from verified round-7 kernel): A[m=lane&15][k=quad*8+j],
// B[n=lane&15][k=quad*8+j], D[row=quad*4+r][col=lane&15].
// QKV=true: N spans 3 weight segments of 1024; per-block bias/scale select;
// bias indexed with SEGMENT-LOCAL column (col0 & 1023) — round-3 OOB fix.
template<int BM, bool RELU, bool RES, bool BIAS, bool QKV, typename TO>
__global__ __launch_bounds__(256)
void gemm_bf16(const u16* __restrict__ A, const u16* __restrict__ Wt,
               const float* __restrict__ bias0, const float* __restrict__ bias1,
               const float* __restrict__ bias2, const float* __restrict__ res,
               TO* __restrict__ C, int M, int N, int K)
{
  constexpr int WM = BM / 2;     // wave M extent
  constexpr int MI = WM / 16;    // A-frags per wave (4 or 2)
  __shared__ u16 As[BM][32];
  __shared__ u16 Bs[128][32];

  const int tid  = threadIdx.x;
  const int wave = tid >> 6;
  const int lane = tid & 63;
  const int lo16 = lane & 15;
  const int quad = lane >> 4;
  const int row0 = blockIdx.y * BM;
  const int col0 = blockIdx.x * 128;
  const int mb   = (wave & 1) * WM;
  const int nb   = (wave >> 1) * 64;

  const float* bias = bias0;
  float osc = 1.0f;
  if (QKV) {
    const int seg = col0 >> 10;              // block fully inside one segment
    bias = (seg == 0) ? bias0 : (seg == 1 ? bias1 : bias2);
    if (seg == 0) osc = 0.125f;              // 1/sqrt(dk) folded into q
  }
  const int bc0 = QKV ? (col0 & 1023) : col0;  // segment-local bias column

  f32x4 acc[MI][4];
#pragma unroll
  for (int i = 0; i < MI; ++i)
#pragma unroll
    for (int j = 0; j < 4; ++j) acc[i][j] = (f32x4){0.f, 0.f, 0.f, 0.f};

  // staging: thread covers 16 B at LDS row s_row, k-chunk s_ch (linear order
  // matches gld_lds's base + lane*16 requirement within each wave)
  const int s_row = tid >> 2;          // 0..63
  const int s_ch  = (tid & 3) * 8;     // bf16 elems
  const u16* gA = A  + (size_t)(row0 + s_row) * K + s_ch;
  const u16* gB = Wt + (size_t)(col0 + s_row) * K + s_ch;

  for (int k0 = 0; k0 < K; k0 += 32) {
    gld_lds16(gA, &As[s_row][s_ch]);
    if constexpr (BM == 128)
      gld_lds16(gA + (size_t)64 * K, &As[s_row + (BM == 128 ? 64 : 0)][s_ch]);
    gld_lds16(gB, &Bs[s_row][s_ch]);
    gld_lds16(gB + (size_t)64 * K, &Bs[s_row + 64][s_ch]);
    gA += 32; gB += 32;
    __syncthreads();

    short8 af[MI], bf[4];
#pragma unroll
    for (int mi = 0; mi < MI; ++mi)
      af[mi] = *(const short8*)&As[mb + mi * 16 + lo16][quad * 8];
#pragma unroll
    for (int ni = 0; ni < 4; ++ni)
      bf[ni] = *(const short8*)&Bs[nb + ni * 16 + lo16][quad * 8];
#pragma unroll
    for (int mi = 0; mi < MI; ++mi)
#pragma unroll
      for (int ni = 0; ni < 4; ++ni)
        acc[mi][ni] = __builtin_amdgcn_mfma_f32_16x16x32_bf16(af[mi], bf[ni], acc[mi][ni], 0, 0, 0);
    __syncthreads();
  }

  // epilogue
  float bv[4];
#pragma unroll
  for (int ni = 0; ni < 4; ++ni)
    bv[ni] = BIAS ? bias[bc0 + nb + ni * 16 + lo16] : 0.f;
#pragma unroll
  for (int mi = 0; mi < MI; ++mi) {
#pragma unroll
    for (int ni = 0; ni < 4; ++ni) {
      const int col = col0 + nb + ni * 16 + lo16;
#pragma unroll
      for (int r = 0; r < 4; ++r) {
        const int row = row0 + mb + mi * 16 + quad * 4 + r;
        float vv = (acc[mi][ni][r] + bv[ni]) * osc;
        if (RELU) vv = fmaxf(vv, 0.f);
        if (RES)  vv += res[(size_t)row * N + col];
        tstore(C + (size_t)row * N + col, vv);
      }
    }
  }
}

// ---------- elementwise fp32 -> bf16 ----------
__global__ __launch_bounds__(256)
void cvt_f2b(const float* __restrict__ in, u16* __restrict__ out)
{
  const size_t i = ((size_t)blockIdx.x * 256 + threadIdx.x) * 8;
  float4 a = *(const float4*)(in + i);
  float4 b = *(const float4*)(in + i + 4);
  uint4 o;
  o.x = (u32)f2b(a.x) | ((u32)f2b(a.y) << 16);
  o.y = (u32)f2b(a.z) | ((u32)f2b(a.w) << 16);
  o.z = (u32)f2b(b.x) | ((u32)f2b(b.y) << 16);
  o.w = (u32)f2b(b.z) | ((u32)f2b(b.w) << 16);
  *(uint4*)(out + i) = o;
}

// ---------- fp32 [R][C] -> bf16 transposed [C][R] (64x64 tiles) ----------
__global__ __launch_bounds__(256)
void transpose_f2b(const float* __restrict__ in, u16* __restrict__ out,
                   int ld_in, int ld_out)
{
  __shared__ u16 tile[64][68];
  const int t  = threadIdx.x;
  const int r0 = blockIdx.x * 64;
  const int c0 = blockIdx.y * 64;
  const int rr = t >> 4;            // 0..15
  const int cc = (t & 15) * 4;      // 0..60
#pragma unroll
  for (int rep = 0; rep < 4; ++rep) {
    float4 v = *(const float4*)(in + (size_t)(r0 + rr + rep * 16) * ld_in + c0 + cc);
    tile[rr + rep * 16][cc + 0] = f2b(v.x);
    tile[rr + rep * 16][cc + 1] = f2b(v.y);
    tile[rr + rep * 16][cc + 2] = f2b(v.z);
    tile[rr + rep * 16][cc + 3] = f2b(v.w);
  }
  __syncthreads();
#pragma unroll
  for (int rep = 0; rep < 4; ++rep) {
    const int dr = rr + rep * 16;   // local c
    uint2 o;
    o.x = (u32)tile[cc + 0][dr] | ((u32)tile[cc + 1][dr] << 16);
    o.y = (u32)tile[cc + 2][dr] | ((u32)tile[cc + 3][dr] << 16);
    *(uint2*)(out + (size_t)(c0 + dr) * ld_out + r0 + cc) = o;
  }
}

// ---------- bf16 transpose with strides (for V -> Vt) ----------
__global__ __launch_bounds__(256)
void transpose_bf16(const u16* __restrict__ in, u16* __restrict__ out,
                    int ld_in, int ld_out)
{
  __shared__ u16 tile[64][68];
  const int t  = threadIdx.x;
  const int r0 = blockIdx.x * 64;   // token dim
  const int c0 = blockIdx.y * 64;   // feature dim
  const int rr = t >> 4;
  const int cc = (t & 15) * 4;
#pragma unroll
  for (int rep = 0; rep < 4; ++rep) {
    uint2 vv = *(const uint2*)(in + (size_t)(r0 + rr + rep * 16) * ld_in + c0 + cc);
    *(uint2*)&tile[rr + rep * 16][cc] = vv;
  }
  __syncthreads();
#pragma unroll
  for (int rep = 0; rep < 4; ++rep) {
    const int dr = rr + rep * 16;
    uint2 o;
    o.x = (u32)tile[cc + 0][dr] | ((u32)tile[cc + 1][dr] << 16);
    o.y = (u32)tile[cc + 2][dr] | ((u32)tile[cc + 3][dr] << 16);
    *(uint2*)(out + (size_t)(c0 + dr) * ld_out + r0 + cc) = o;
  }
}

// ---------- MFMA attention, head-axis softmax, producer/consumer ----------
// Block = 16 q-rows, 1024 threads (16 waves), grid 256 = 1 block/CU.
// q/k row stride = QKV_LD (fused qkv buffer); ctx -> d_out.
__global__ __launch_bounds__(1024)
void attention_mfma(const u16* __restrict__ q, const u16* __restrict__ k,
                    const u16* __restrict__ vt, u16* __restrict__ ctx)
{
  __shared__ __align__(16) u16 Ws[2][16][16][128];  // 131,072 B

  const int tid  = threadIdx.x;
  const int wave = tid >> 6;
  const int lane = tid & 63;
  const int lo16 = lane & 15;
  const int quad = lane >> 4;

  const int qrow0 = blockIdx.x * 16;
  const int batch = blockIdx.x >> 7;

  if (wave < 8) {
    // ================= producer =================
    const int tloc = wave * 16;
    const u16* qrow = q + (size_t)(qrow0 + lo16) * QKV_LD + quad * 8;
    const u16* kbp  = k + (size_t)batch * S_ * QKV_LD;

    for (int s = 0; s < 16; ++s) {
      const int t0 = s * 128;
      u16 (*W)[16][128] = Ws[s & 1];
      const u16* krow = kbp + (size_t)(t0 + tloc + lo16) * QKV_LD + quad * 8;

      f32x4 Sg[16];
#pragma unroll
      for (int h = 0; h < 16; ++h) {
        short8 a0 = *(const short8*)(qrow + h * 64);
        short8 b0 = *(const short8*)(krow + h * 64);
        short8 a1 = *(const short8*)(qrow + h * 64 + 32);
        short8 b1 = *(const short8*)(krow + h * 64 + 32);
        f32x4 sc = (f32x4){0.f, 0.f, 0.f, 0.f};
        sc = __builtin_amdgcn_mfma_f32_16x16x32_bf16(a0, b0, sc, 0, 0, 0);
        sc = __builtin_amdgcn_mfma_f32_16x16x32_bf16(a1, b1, sc, 0, 0, 0);
        Sg[h] = sc;
      }
#pragma unroll
      for (int r = 0; r < 4; ++r) {
        float m = Sg[0][r];
#pragma unroll
        for (int h = 1; h < 16; ++h) m = fmaxf(m, Sg[h][r]);
        float sum = 0.f;
#pragma unroll
        for (int h = 0; h < 16; ++h) {
          float e = __expf(Sg[h][r] - m);
          Sg[h][r] = e;
          sum += e;
        }
        float rinv = 1.0f / sum;
        const int qq  = quad * 4 + r;
        const int pos = (tloc + lo16) ^ ((qq & 7) << 3);
#pragma unroll
        for (int h = 0; h < 16; ++h) {
          union { float f; u32 u; } z; z.f = Sg[h][r] * rinv;
          W[h][qq][pos] = (u16)((z.u + 0x8000u) >> 16);
        }
      }
      __syncthreads();   // publish Ws[s&1]
    }
    __syncthreads();     // pair with consumer's final in-loop barrier
  } else {
    // ================= consumer =================
    const int h0 = (wave - 8) * 2;
    f32x4 acc[2][4];
#pragma unroll
    for (int i = 0; i < 2; ++i)
#pragma unroll
      for (int j = 0; j < 4; ++j) acc[i][j] = (f32x4){0.f, 0.f, 0.f, 0.f};

    const u16* vbase[2][4];
#pragma unroll
    for (int hh = 0; hh < 2; ++hh)
#pragma unroll
      for (int dt = 0; dt < 4; ++dt)
        vbase[hh][dt] = vt + (size_t)((h0 + hh) * 64 + dt * 16 + lo16) * M_
                           + (size_t)batch * S_ + quad * 8;

    __syncthreads();     // wait for Ws[0]
    for (int s = 0; s < 16; ++s) {
      const int t0 = s * 128;
      const u16 (*W)[16][128] = Ws[s & 1];
#pragma unroll
      for (int kc = 0; kc < 4; ++kc) {
        const int kbase = kc * 32 + quad * 8;
        const int ksw   = kbase ^ ((lo16 & 7) << 3);
#pragma unroll
        for (int hh = 0; hh < 2; ++hh) {
          short8 aw = *(const short8*)&W[h0 + hh][lo16][ksw];
#pragma unroll
          for (int dt = 0; dt < 4; ++dt) {
            short8 bv = *(const short8*)(vbase[hh][dt] + t0 + kc * 32);
            acc[hh][dt] = __builtin_amdgcn_mfma_f32_16x16x32_bf16(aw, bv, acc[hh][dt], 0, 0, 0);
          }
        }
      }
      __syncthreads();
    }

    u16* crow = ctx + (size_t)(qrow0 + quad * 4) * D_ + lo16;
#pragma unroll
    for (int hh = 0; hh < 2; ++hh)
#pragma unroll
      for (int dt = 0; dt < 4; ++dt)
#pragma unroll
        for (int r = 0; r < 4; ++r)
          crow[(size_t)r * D_ + (h0 + hh) * 64 + dt * 16] = f2b(acc[hh][dt][r]);
  }
}

// ---------- (x [+ y]) -> LayerNorm (D=1024, one block per row) ----------
__device__ __forceinline__ float block_sum(float vv, float* sm) {
#pragma unroll
  for (int o = 32; o > 0; o >>= 1) vv += __shfl_down(vv, o);
  __syncthreads();
  if ((threadIdx.x & 63) == 0) sm[threadIdx.x >> 6] = vv;
  __syncthreads();
  return sm[0] + sm[1] + sm[2] + sm[3];
}

// out fp32; AUX additionally writes bf16 copy (feeds next GEMM's A)
template<bool HAS_Y, bool AUX>
__global__ __launch_bounds__(256)
void add_ln(const float* __restrict__ x, const u16* __restrict__ y,
            const float* __restrict__ g, const float* __restrict__ bta,
            float* __restrict__ out, u16* __restrict__ aux)
{
  __shared__ float sm[4];
  const int row = blockIdx.x;
  const int t   = threadIdx.x;
  const size_t base = (size_t)row * D_ + t * 4;

  float s[4];
  load4(x + base, s);
  if (HAS_Y) {
    float yv[4];
    load4(y + base, yv);
    s[0] += yv[0]; s[1] += yv[1]; s[2] += yv[2]; s[3] += yv[3];
  }

  float loc = s[0] + s[1] + s[2] + s[3];
  float tot = block_sum(loc, sm);
  float mean = tot * (1.f / 1024.f);
  float d0 = s[0] - mean, d1 = s[1] - mean, d2 = s[2] - mean, d3 = s[3] - mean;
  float sq = d0 * d0 + d1 * d1 + d2 * d2 + d3 * d3;
  float tv = block_sum(sq, sm);
  float rstd = rsqrtf(tv * (1.f / 1024.f) + 1e-5f);

  float4 gv = *(const float4*)(g + t * 4);
  float4 bv = *(const float4*)(bta + t * 4);
  float o0 = d0 * rstd * gv.x + bv.x;
  float o1 = d1 * rstd * gv.y + bv.y;
  float o2 = d2 * rstd * gv.z + bv.z;
  float o3 = d3 * rstd * gv.w + bv.w;
  *(float4*)(out + base) = make_float4(o0, o1, o2, o3);
  if (AUX) {
    uint2 ov;
    ov.x = (u32)f2b(o0) | ((u32)f2b(o1) << 16);
    ov.y = (u32)f2b(o2) | ((u32)f2b(o3) << 16);
    *(uint2*)(aux + base) = ov;
  }
}

// ---------- launch ----------
// ws = 32 MiB exactly; d_out (16 MiB fp32) doubles as scratch.
// Schedule / lifetimes (MiB offsets into ws):
//   phase QKV : xb=d_out[0..8) bf16(x); wqkvt@24..30; qkv@0..24 [4096][3072]
//   phase attn: vt@24..32 (wqkvt dead); ctx=d_out (xb dead)
//   phase proj: wot@16..18, ao@8..16 (qkv dead)
//   phase LN1 : x1=d_out fp32 (ctx dead), x1b@0..8
//   phase FFN : w1t@8..12, w2t@12..16, h1@16..32 [4096][2048] (two DFF halves)
extern "C" void kernel_launch(void* const* d_in, const int* in_sizes, int n_in,
                              void* d_out, int out_size, void* d_ws, size_t ws_size,
                              hipStream_t stream) {
  const float* x     = (const float*)d_in[0];
  const float* wq    = (const float*)d_in[1];
  const float* bq    = (const float*)d_in[2];
  const float* wk    = (const float*)d_in[3];
  const float* bk    = (const float*)d_in[4];
  const float* wv    = (const float*)d_in[5];
  const float* bv    = (const float*)d_in[6];
  const float* wo    = (const float*)d_in[7];
  const float* bo    = (const float*)d_in[8];
  const float* g1    = (const float*)d_in[9];
  const float* beta1 = (const float*)d_in[10];
  const float* w1    = (const float*)d_in[11];
  const float* b1    = (const float*)d_in[12];
  const float* w2    = (const float*)d_in[13];
  const float* b2    = (const float*)d_in[14];
  const float* g2    = (const float*)d_in[15];
  const float* beta2 = (const float*)d_in[16];
  float* outF = (float*)d_out;

  char* wsb = (char*)d_ws;
  const size_t MiB = (size_t)1 << 20;
  u16* qkv   = (u16*)(wsb + 0);
  u16* wqkvt = (u16*)(wsb + 24 * MiB);
  u16* vt    = (u16*)(wsb + 24 * MiB);
  u16* ao    = (u16*)(wsb + 8 * MiB);
  u16* wot   = (u16*)(wsb + 16 * MiB);
  u16* x1b   = (u16*)(wsb + 0);
  u16* w1t   = (u16*)(wsb + 8 * MiB);
  u16* w2t   = (u16*)(wsb + 12 * MiB);
  u16* h1    = (u16*)(wsb + 16 * MiB);
  u16* xb    = (u16*)d_out;
  u16* ctx   = (u16*)d_out;
  float* x1  = outF;
  float* z   = outF;

  dim3 blk(256);
  // x -> bf16 (into d_out scratch)
  cvt_f2b<<<dim3((M_ * D_) / (256 * 8)), blk, 0, stream>>>(x, xb);
  // weight transposes for fused QKV: wqkvt rows [0,1024)=wq^T, [1024,2048)=wk^T, [2048,3072)=wv^T
  transpose_f2b<<<dim3(16, 16), blk, 0, stream>>>(wq, wqkvt,                 D_, D_);
  transpose_f2b<<<dim3(16, 16), blk, 0, stream>>>(wk, wqkvt + 1024 * 1024,   D_, D_);
  transpose_f2b<<<dim3(16, 16), blk, 0, stream>>>(wv, wqkvt + 2048 * 1024,   D_, D_);
  // fused QKV GEMM: [4096][3072], q-segment scaled by 0.125
  gemm_bf16<128, false, false, true, true, u16><<<dim3(QKV_LD / 128, M_ / 128), blk, 0, stream>>>(
      xb, wqkvt, bq, bk, bv, nullptr, qkv, M_, QKV_LD, D_);
  // Vt = V^T (V = qkv cols [2048,3072), row stride 3072)
  transpose_bf16<<<dim3(M_ / 64, 1024 / 64), blk, 0, stream>>>(qkv + 2048, vt, QKV_LD, M_);
  // fused MFMA attention (head-axis softmax), producer/consumer waves
  attention_mfma<<<dim3(M_ / 16), dim3(1024), 0, stream>>>(qkv, qkv + 1024, vt, ctx);
  // output projection (BM=64 -> grid 512, 2 blocks/CU)
  transpose_f2b<<<dim3(16, 16), blk, 0, stream>>>(wo, wot, D_, D_);
  gemm_bf16<64, false, false, true, false, u16><<<dim3(D_ / 128, M_ / 64), blk, 0, stream>>>(
      ctx, wot, bo, nullptr, nullptr, nullptr, ao, M_, D_, D_);
  // x1 = LN(x + attn_out), fp32 to d_out + bf16 aux
  add_ln<true, true><<<dim3(M_), blk, 0, stream>>>(x, ao, g1, beta1, x1, x1b);
  // FFN in two DFF halves (h1 half = 16 MiB)
  // half a: cols [0,2048) of w1, rows [0,2048) of w2
  transpose_f2b<<<dim3(16, 32), blk, 0, stream>>>(w1, w1t, DFF_, D_);
  transpose_f2b<<<dim3(32, 16), blk, 0, stream>>>(w2, w2t, D_, 2048);
  gemm_bf16<128, true, false, true, false, u16><<<dim3(2048 / 128, M_ / 128), blk, 0, stream>>>(
      x1b, w1t, b1, nullptr, nullptr, nullptr, h1, M_, 2048, D_);
  gemm_bf16<64, false, true, false, false, float><<<dim3(D_ / 128, M_ / 64), blk, 0, stream>>>(
      h1, w2t, nullptr, nullptr, nullptr, x1, z, M_, D_, 2048);
  // half b: cols [2048,4096) of w1, rows [2048,4096) of w2; adds b2
  transpose_f2b<<<dim3(16, 32), blk, 0, stream>>>(w1 + 2048, w1t, DFF_, D_);
  transpose_f2b<<<dim3(32, 16), blk, 0, stream>>>(w2 + (size_t)2048 * 1024, w2t, D_, 2048);
  gemm_bf16<128, true, false, true, false, u16><<<dim3(2048 / 128, M_ / 128), blk, 0, stream>>>(
      x1b, w1t, b1 + 2048, nullptr, nullptr, nullptr, h1, M_, 2048, D_);
  gemm_bf16<64, false, true, true, false, float><<<dim3(D_ / 128, M_ / 64), blk, 0, stream>>>(
      h1, w2t, b2, nullptr, nullptr, z, z, M_, D_, 2048);
  // out = LN(z), in-place on d_out
  add_ln<false, false><<<dim3(M_), blk, 0, stream>>>(z, nullptr, g2, beta2, outF, nullptr);
}